// Round 10
// baseline (456.363 us; speedup 1.0000x reference)
//
#include <hip/hip_runtime.h>

#define NPTS   50000
#define NEDGE  800000
#define NTILES 50000   // NEDGE/16
#define NPAIRS 25000   // NTILES/2
#define NBLK   768     // persistent: 3 blocks/CU * 256 CU
#define WS_CNT (NPTS * 64)   // byte offset of steal counter (after 3.2MB record table)

typedef short  bf16x8 __attribute__((ext_vector_type(8)));
typedef float  f32x4  __attribute__((ext_vector_type(4)));
typedef int    i32x4  __attribute__((ext_vector_type(4)));
typedef unsigned short u16x8 __attribute__((ext_vector_type(8)));

// tanh-form GELU, |err| <= ~3e-4 vs exact erf gelu (threshold 0.171; measured absmax 0.03)
__device__ __forceinline__ float gelu_tanh(float v) {
    float v2 = v * v;
    float u2 = v * fmaf(v2, 0.0713548162726f, 1.5957691216057f);
    float e  = __expf(u2);
    float r  = __builtin_amdgcn_rcpf(e + 1.0f);
    return v - v * r;
}

__device__ __forceinline__ unsigned short f2bf(float f) {
    unsigned u = __builtin_bit_cast(unsigned, f);
    unsigned r = (u + 0x7FFFu + ((u >> 16) & 1u)) >> 16;
    return (unsigned short)r;
}
__device__ __forceinline__ float bf2f(unsigned short h) {
    return __builtin_bit_cast(float, (unsigned)h << 16);
}

__device__ __forceinline__ int cvt_pk_bf16(float a, float b) {
    int r;
    asm("v_cvt_pk_bf16_f32 %0, %1, %2" : "=v"(r) : "v"(a), "v"(b));
    return r;
}

__device__ __forceinline__ int bperm(int addr, int v) {
    return __builtin_amdgcn_ds_bpermute(addr, v);
}
__device__ __forceinline__ int fbits(float v) { return __builtin_bit_cast(int, v); }
__device__ __forceinline__ float ibits(int v) { return __builtin_bit_cast(float, v); }

// prep: zero out, build 64B node records {bf16 x[16] | bf16 pos[3] | pad}, zero counter
__global__ void prep_kernel(const float* __restrict__ x, const float* __restrict__ pos,
                            float* __restrict__ out, unsigned short* __restrict__ nrec,
                            int* __restrict__ cnt) {
    int i = blockIdx.x * 256 + threadIdx.x;
    if (i == 0) *cnt = 0;
    if (i < NPTS * 16) out[i] = 0.0f;
    if (i < NPTS) {
        const float4* xp = reinterpret_cast<const float4*>(x + (size_t)i * 16);
        float4 a = xp[0], b = xp[1], c = xp[2], d = xp[3];
        u16x8 r0, r1, r2, r3;
        r0[0]=f2bf(a.x); r0[1]=f2bf(a.y); r0[2]=f2bf(a.z); r0[3]=f2bf(a.w);
        r0[4]=f2bf(b.x); r0[5]=f2bf(b.y); r0[6]=f2bf(b.z); r0[7]=f2bf(b.w);
        r1[0]=f2bf(c.x); r1[1]=f2bf(c.y); r1[2]=f2bf(c.z); r1[3]=f2bf(c.w);
        r1[4]=f2bf(d.x); r1[5]=f2bf(d.y); r1[6]=f2bf(d.z); r1[7]=f2bf(d.w);
        r2[0]=f2bf(pos[i*3+0]); r2[1]=f2bf(pos[i*3+1]); r2[2]=f2bf(pos[i*3+2]);
        r2[3]=0; r2[4]=0; r2[5]=0; r2[6]=0; r2[7]=0;
        r3[0]=0; r3[1]=0; r3[2]=0; r3[3]=0; r3[4]=0; r3[5]=0; r3[6]=0; r3[7]=0;
        u16x8* dst = reinterpret_cast<u16x8*>(nrec + (size_t)i * 32);
        dst[0] = r0; dst[1] = r1; dst[2] = r2; dst[3] = r3;
    }
}

// Transposed-operand MFMA + 2-tile pipeline, persistent blocks, work-stealing pairs.
__global__ __launch_bounds__(512, 4) void edge_mfma_kernel(
    const unsigned short* __restrict__ nrec, // [NPTS*32] 64B records
    const int*   __restrict__ ei,            // [2*NEDGE]
    const float* __restrict__ W1,
    const float* __restrict__ b1,
    const float* __restrict__ Wh,
    const float* __restrict__ bh,
    const float* __restrict__ Wo,
    const float* __restrict__ bo,
    float* __restrict__ out,                 // [NPTS*16]
    int* __restrict__ cnt)
{
    __shared__ bf16x8 WoF[32][64];
    __shared__ bf16x8 WhF[8][64];
    __shared__ bf16x8 W1F[4][64];
    __shared__ bf16x8 BOF[64];
    __shared__ float  bhs[64];

    const int tid = threadIdx.x;

    // ---- stage weight fragments (once per persistent block) ----
#pragma unroll
    for (int p = 0; p < 4; ++p) {
        int e_id = p * 512 + tid;
        int s  = e_id >> 6;
        int l  = e_id & 63;
        int er_ = l & 15, g = l >> 4;
        int i  = s >> 1, kt = s & 1;
        int n  = i * 16 + er_;
        int kb = kt * 32 + g * 8;
        bf16x8 f;
#pragma unroll
        for (int j = 0; j < 8; ++j)
            f[j] = (short)f2bf(Wo[(kb + j) * 256 + n]);
        WoF[s][l] = f;
    }
    {
        int s  = tid >> 6;
        int l  = tid & 63;
        int er_ = l & 15, g = l >> 4;
        int m  = s >> 1, kt = s & 1;
        int n  = m * 16 + er_;
        int kb = kt * 32 + g * 8;
        bf16x8 f;
#pragma unroll
        for (int j = 0; j < 8; ++j)
            f[j] = (short)f2bf(Wh[(kb + j) * 64 + n]);
        WhF[s][l] = f;
    }
    if (tid < 256) {
        int m  = tid >> 6;
        int l  = tid & 63;
        int er_ = l & 15, g = l >> 4;
        int n  = m * 16 + er_;
        bf16x8 f;
#pragma unroll
        for (int j = 0; j < 8; ++j) {
            int k = g * 8 + j;
            float v = (k < 6) ? W1[k * 64 + n] : (k == 6 ? b1[n] : 0.0f);
            f[j] = (short)f2bf(v);
        }
        W1F[m][l] = f;
    }
    if (tid < 64) {
        int er_ = tid & 15, g = tid >> 4;
        bf16x8 f;
#pragma unroll
        for (int j = 0; j < 8; ++j) {
            int i = g * 8 + j;
            f[j] = (g < 2) ? (short)f2bf(bo[i * 16 + er_]) : (short)0;
        }
        BOF[tid] = f;
        bhs[tid] = bh[tid];
    }
    __syncthreads();

    const int wave = tid >> 6;
    const int lane = tid & 63;
    const int grp  = lane >> 4;
    const int er   = lane & 15;

    const int addrH0 = (er + (grp & 1) * 32) * 4;
    const int addrH1 = addrH0 + 64;
    const bool selHi = (grp >= 2);
    int addrT[4], addrD[4];
#pragma unroll
    for (int r = 0; r < 4; ++r) {
        addrT[r] = ((er >> 2) * 16 + grp * 4 + r) * 4;
        addrD[r] = (grp * 4 + r) * 4;
    }
    const int selT = er & 3;

    const bf16x8* wof = &WoF[0][lane];
    const bf16x8* whf = &WhF[0][lane];
    const bf16x8* w1f = &W1F[0][lane];
    const bf16x8  bofr = BOF[lane];
    const f32x4 zero = {0.f, 0.f, 0.f, 0.f};

    // ---- work-stealing: wave-uniform pair index, prefetched one iter ahead ----
    int myp;
    {
        int v = 0;
        if (lane == 0) v = atomicAdd(cnt, 1);
        myp = __builtin_amdgcn_readfirstlane(v);
    }

#pragma unroll 1
    while (myp < NPAIRS) {
        // prefetch next pair index (latency hides under this pair's compute)
        int nxt;
        {
            int v = 0;
            if (lane == 0) v = atomicAdd(cnt, 1);
            nxt = __builtin_amdgcn_readfirstlane(v);
        }
        const int pr = myp;

        // ---- per-pair loads from 64B node records; lane's edge = er ----
        int dQ[2];
        bf16x8 apeQ[2];
        u16x8 xA[2], xB[2];
#pragma unroll
        for (int q = 0; q < 2; ++q) {
            const int eb = (2 * pr + q) << 4;
            int s = ei[eb + er];
            int d = ei[NEDGE + eb + er];
            s = min(max(s, 0), NPTS - 1);
            d = min(max(d, 0), NPTS - 1);
            dQ[q] = d;

            const u16x8* rp = reinterpret_cast<const u16x8*>(nrec + (size_t)s * 32);
            xA[q] = rp[0];
            xB[q] = rp[1];
            ushort4 ps = *reinterpret_cast<const ushort4*>(nrec + (size_t)s * 32 + 16);
            ushort4 pd = *reinterpret_cast<const ushort4*>(nrec + (size_t)d * 32 + 16);

            const bool g0 = (grp == 0);
            bf16x8 ap;
            ap[0] = g0 ? (short)ps.x : (short)0;
            ap[1] = g0 ? (short)ps.y : (short)0;
            ap[2] = g0 ? (short)ps.z : (short)0;
            ap[3] = g0 ? (short)pd.x : (short)0;
            ap[4] = g0 ? (short)pd.y : (short)0;
            ap[5] = g0 ? (short)pd.z : (short)0;
            ap[6] = g0 ? (short)0x3F80 : (short)0;   // bf16(1.0) -> b1 rides k==6
            ap[7] = 0;
            apeQ[q] = ap;
        }

        // ---- layer 1 ----
        float g1[2][4][4];
#pragma unroll
        for (int q = 0; q < 2; ++q)
#pragma unroll
            for (int m = 0; m < 4; ++m) {
                f32x4 c = __builtin_amdgcn_mfma_f32_16x16x32_bf16(w1f[m * 64], apeQ[q], zero, 0, 0, 0);
#pragma unroll
                for (int r = 0; r < 4; ++r) g1[q][m][r] = gelu_tanh(c[r]);
            }

        // ---- B2 frags: pack-then-permute ----
        bf16x8 B2[2][2];
#pragma unroll
        for (int q = 0; q < 2; ++q)
#pragma unroll
            for (int kt = 0; kt < 2; ++kt) {
                int pk0[2], pk1[2];
#pragma unroll
                for (int rp = 0; rp < 2; ++rp) {
                    pk0[rp] = cvt_pk_bf16(g1[q][2 * kt + 0][2 * rp], g1[q][2 * kt + 0][2 * rp + 1]);
                    pk1[rp] = cvt_pk_bf16(g1[q][2 * kt + 1][2 * rp], g1[q][2 * kt + 1][2 * rp + 1]);
                }
                i32x4 w;
#pragma unroll
                for (int h = 0; h < 2; ++h) {
                    int ah = h ? addrH1 : addrH0;
#pragma unroll
                    for (int rp = 0; rp < 2; ++rp) {
                        int vA = bperm(ah, pk0[rp]);
                        int vB = bperm(ah, pk1[rp]);
                        w[h * 2 + rp] = selHi ? vB : vA;
                    }
                }
                B2[q][kt] = __builtin_bit_cast(bf16x8, w);
            }

        // ---- layer 2 ----
        float g2[2][4][4];
#pragma unroll
        for (int q = 0; q < 2; ++q)
#pragma unroll
            for (int m = 0; m < 4; ++m) {
                f32x4 c = __builtin_amdgcn_mfma_f32_16x16x32_bf16(whf[(2 * m + 0) * 64], B2[q][0], zero, 0, 0, 0);
                c = __builtin_amdgcn_mfma_f32_16x16x32_bf16(whf[(2 * m + 1) * 64], B2[q][1], c, 0, 0, 0);
                float4 b4 = *reinterpret_cast<const float4*>(&bhs[m * 16 + grp * 4]);
                float bb[4] = {b4.x, b4.y, b4.z, b4.w};
#pragma unroll
                for (int r = 0; r < 4; ++r) g2[q][m][r] = gelu_tanh(c[r] + bb[r]);
            }

        // ---- B3 frags ----
        bf16x8 B3[2][2];
#pragma unroll
        for (int q = 0; q < 2; ++q)
#pragma unroll
            for (int kt = 0; kt < 2; ++kt) {
                int pk0[2], pk1[2];
#pragma unroll
                for (int rp = 0; rp < 2; ++rp) {
                    pk0[rp] = cvt_pk_bf16(g2[q][2 * kt + 0][2 * rp], g2[q][2 * kt + 0][2 * rp + 1]);
                    pk1[rp] = cvt_pk_bf16(g2[q][2 * kt + 1][2 * rp], g2[q][2 * kt + 1][2 * rp + 1]);
                }
                i32x4 w;
#pragma unroll
                for (int h = 0; h < 2; ++h) {
                    int ah = h ? addrH1 : addrH0;
#pragma unroll
                    for (int rp = 0; rp < 2; ++rp) {
                        int vA = bperm(ah, pk0[rp]);
                        int vB = bperm(ah, pk1[rp]);
                        w[h * 2 + rp] = selHi ? vB : vA;
                    }
                }
                B3[q][kt] = __builtin_bit_cast(bf16x8, w);
            }

        // ---- bo contribution: msg = BOF @ X^T (x already bf16) ----
        f32x4 msg[2];
#pragma unroll
        for (int q = 0; q < 2; ++q) {
            bf16x8 xb;
#pragma unroll
            for (int j = 0; j < 8; ++j) {
                short v = (grp == 0) ? (short)xA[q][j] : ((grp == 1) ? (short)xB[q][j] : (short)0);
                xb[j] = v;
            }
            msg[q] = __builtin_amdgcn_mfma_f32_16x16x32_bf16(bofr, xb, zero, 0, 0, 0);
        }

        // ---- layer 3 + einsum ----
#pragma unroll
        for (int i = 0; i < 16; ++i)
#pragma unroll
            for (int q = 0; q < 2; ++q) {
                f32x4 c = __builtin_amdgcn_mfma_f32_16x16x32_bf16(wof[(2 * i + 0) * 64], B3[q][0], zero, 0, 0, 0);
                c = __builtin_amdgcn_mfma_f32_16x16x32_bf16(wof[(2 * i + 1) * 64], B3[q][1], c, 0, 0, 0);
                float xf = bf2f(i < 8 ? xA[q][i] : xB[q][i - 8]);
#pragma unroll
                for (int r = 0; r < 4; ++r)
                    msg[q][r] = fmaf(xf, c[r], msg[q][r]);
            }

        // ---- transpose msg across lanes -> line-packed atomics (64B/edge) ----
#pragma unroll
        for (int q = 0; q < 2; ++q) {
#pragma unroll
            for (int rd = 0; rd < 4; ++rd) {
                int u0 = bperm(addrT[rd], fbits(msg[q][0]));
                int u1 = bperm(addrT[rd], fbits(msg[q][1]));
                int u2 = bperm(addrT[rd], fbits(msg[q][2]));
                int u3 = bperm(addrT[rd], fbits(msg[q][3]));
                int v  = (selT == 0) ? u0 : (selT == 1) ? u1 : (selT == 2) ? u2 : u3;
                int dv = bperm(addrD[rd], dQ[q]);
                atomicAdd(out + (size_t)dv * 16 + er, ibits(v));
            }
        }

        myp = nxt;
    }
}

extern "C" void kernel_launch(void* const* d_in, const int* in_sizes, int n_in,
                              void* d_out, int out_size, void* d_ws, size_t ws_size,
                              hipStream_t stream) {
    const float* x   = (const float*)d_in[0];
    const float* pos = (const float*)d_in[1];
    const int*   ei  = (const int*)d_in[2];
    const float* W1  = (const float*)d_in[3];
    const float* b1  = (const float*)d_in[4];
    const float* Wh  = (const float*)d_in[5];
    const float* bh  = (const float*)d_in[6];
    const float* Wo  = (const float*)d_in[7];
    const float* bo  = (const float*)d_in[8];
    float* out = (float*)d_out;

    unsigned short* nrec = (unsigned short*)d_ws;        // 3.2 MB record table
    int* cnt = (int*)((char*)d_ws + WS_CNT);             // steal counter

    prep_kernel<<<(NPTS * 16 + 255) / 256, 256, 0, stream>>>(x, pos, out, nrec, cnt);
    edge_mfma_kernel<<<NBLK, 512, 0, stream>>>(
        nrec, ei, W1, b1, Wh, bh, Wo, bo, out, cnt);
}

// Round 11
// 167.419 us; speedup vs baseline: 2.7259x; 2.7259x over previous
//
#include <hip/hip_runtime.h>

#define NPTS   50000
#define NEDGE  800000
#define NTILES 50000   // NEDGE/16
#define NPAIRS 25000   // NTILES/2
#define NBLK   768     // persistent: 3 blocks/CU * 256 CU
#define TOTW   (NBLK * 8)

typedef short  bf16x8 __attribute__((ext_vector_type(8)));
typedef float  f32x4  __attribute__((ext_vector_type(4)));
typedef int    i32x4  __attribute__((ext_vector_type(4)));
typedef unsigned short u16x8 __attribute__((ext_vector_type(8)));

// tanh-form GELU, |err| <= ~3e-4 vs exact erf gelu (threshold 0.171; measured absmax 0.03)
__device__ __forceinline__ float gelu_tanh(float v) {
    float v2 = v * v;
    float u2 = v * fmaf(v2, 0.0713548162726f, 1.5957691216057f);
    float e  = __expf(u2);
    float r  = __builtin_amdgcn_rcpf(e + 1.0f);
    return v - v * r;
}

__device__ __forceinline__ unsigned short f2bf(float f) {
    unsigned u = __builtin_bit_cast(unsigned, f);
    unsigned r = (u + 0x7FFFu + ((u >> 16) & 1u)) >> 16;
    return (unsigned short)r;
}
__device__ __forceinline__ float bf2f(unsigned short h) {
    return __builtin_bit_cast(float, (unsigned)h << 16);
}

__device__ __forceinline__ int cvt_pk_bf16(float a, float b) {
    int r;
    asm("v_cvt_pk_bf16_f32 %0, %1, %2" : "=v"(r) : "v"(a), "v"(b));
    return r;
}

__device__ __forceinline__ int bperm(int addr, int v) {
    return __builtin_amdgcn_ds_bpermute(addr, v);
}
__device__ __forceinline__ int fbits(float v) { return __builtin_bit_cast(int, v); }
__device__ __forceinline__ float ibits(int v) { return __builtin_bit_cast(float, v); }

// fused prep: zero out + build bf16 x-table (32B records, pos stays in f32 table)
__global__ void prep_kernel(const float* __restrict__ x, float* __restrict__ out,
                            unsigned short* __restrict__ xbf) {
    int i = blockIdx.x * 256 + threadIdx.x;
    if (i < NPTS * 16) out[i] = 0.0f;
    if (i < (NPTS * 16) / 4) {
        float4 v = reinterpret_cast<const float4*>(x)[i];
        ushort4 o;
        o.x = f2bf(v.x);
        o.y = f2bf(v.y);
        o.z = f2bf(v.z);
        o.w = f2bf(v.w);
        reinterpret_cast<ushort4*>(xbf)[i] = o;
    }
}

// Transposed-operand MFMA + 2-tile pipeline, persistent blocks (static grid-stride over pairs).
__global__ __launch_bounds__(512, 4) void edge_mfma_kernel(
    const unsigned short* __restrict__ xbf,  // [NPTS*16] bf16
    const float* __restrict__ pos,           // [NPTS*3] (f32, L2-resident)
    const int*   __restrict__ ei,            // [2*NEDGE]
    const float* __restrict__ W1,
    const float* __restrict__ b1,
    const float* __restrict__ Wh,
    const float* __restrict__ bh,
    const float* __restrict__ Wo,
    const float* __restrict__ bo,
    float* __restrict__ out)                 // [NPTS*16]
{
    __shared__ bf16x8 WoF[32][64];
    __shared__ bf16x8 WhF[8][64];
    __shared__ bf16x8 W1F[4][64];
    __shared__ bf16x8 BOF[64];
    __shared__ float  bhs[64];

    const int tid = threadIdx.x;

    // ---- stage weight fragments (once per persistent block) ----
#pragma unroll
    for (int p = 0; p < 4; ++p) {
        int e_id = p * 512 + tid;
        int s  = e_id >> 6;
        int l  = e_id & 63;
        int er_ = l & 15, g = l >> 4;
        int i  = s >> 1, kt = s & 1;
        int n  = i * 16 + er_;
        int kb = kt * 32 + g * 8;
        bf16x8 f;
#pragma unroll
        for (int j = 0; j < 8; ++j)
            f[j] = (short)f2bf(Wo[(kb + j) * 256 + n]);
        WoF[s][l] = f;
    }
    {
        int s  = tid >> 6;
        int l  = tid & 63;
        int er_ = l & 15, g = l >> 4;
        int m  = s >> 1, kt = s & 1;
        int n  = m * 16 + er_;
        int kb = kt * 32 + g * 8;
        bf16x8 f;
#pragma unroll
        for (int j = 0; j < 8; ++j)
            f[j] = (short)f2bf(Wh[(kb + j) * 64 + n]);
        WhF[s][l] = f;
    }
    if (tid < 256) {
        int m  = tid >> 6;
        int l  = tid & 63;
        int er_ = l & 15, g = l >> 4;
        int n  = m * 16 + er_;
        bf16x8 f;
#pragma unroll
        for (int j = 0; j < 8; ++j) {
            int k = g * 8 + j;
            float v = (k < 6) ? W1[k * 64 + n] : (k == 6 ? b1[n] : 0.0f);
            f[j] = (short)f2bf(v);
        }
        W1F[m][l] = f;
    }
    if (tid < 64) {
        int er_ = tid & 15, g = tid >> 4;
        bf16x8 f;
#pragma unroll
        for (int j = 0; j < 8; ++j) {
            int i = g * 8 + j;
            f[j] = (g < 2) ? (short)f2bf(bo[i * 16 + er_]) : (short)0;
        }
        BOF[tid] = f;
        bhs[tid] = bh[tid];
    }
    __syncthreads();

    const int wave = tid >> 6;
    const int lane = tid & 63;
    const int grp  = lane >> 4;
    const int er   = lane & 15;

    const int addrH0 = (er + (grp & 1) * 32) * 4;
    const int addrH1 = addrH0 + 64;
    const bool selHi = (grp >= 2);
    int addrT[4], addrD[4];
#pragma unroll
    for (int r = 0; r < 4; ++r) {
        addrT[r] = ((er >> 2) * 16 + grp * 4 + r) * 4;
        addrD[r] = (grp * 4 + r) * 4;
    }
    const int selT = er & 3;

    const bf16x8* wof = &WoF[0][lane];
    const bf16x8* whf = &WhF[0][lane];
    const bf16x8* w1f = &W1F[0][lane];
    const bf16x8  bofr = BOF[lane];
    const f32x4 zero = {0.f, 0.f, 0.f, 0.f};

    const int gwave = blockIdx.x * 8 + wave;   // 0..TOTW-1

#pragma unroll 1
    for (int pr = gwave; pr < NPAIRS; pr += TOTW) {
        // ---- per-pair loads: tiles 2*pr, 2*pr+1; lane's edge = er ----
        int sQ[2], dQ[2];
        bf16x8 apeQ[2];
        u16x8 xA[2], xB[2];
#pragma unroll
        for (int q = 0; q < 2; ++q) {
            const int eb = (2 * pr + q) << 4;
            int s = ei[eb + er];
            int d = ei[NEDGE + eb + er];
            s = min(max(s, 0), NPTS - 1);
            d = min(max(d, 0), NPTS - 1);
            sQ[q] = s; dQ[q] = d;

            const u16x8* xp = reinterpret_cast<const u16x8*>(xbf + (size_t)s * 16);
            xA[q] = xp[0];
            xB[q] = xp[1];

            float p0 = pos[s * 3 + 0], p1 = pos[s * 3 + 1], p2 = pos[s * 3 + 2];
            float p3 = pos[d * 3 + 0], p4 = pos[d * 3 + 1], p5 = pos[d * 3 + 2];
            const bool g0 = (grp == 0);
            bf16x8 ap;
            ap[0] = g0 ? (short)f2bf(p0) : (short)0;
            ap[1] = g0 ? (short)f2bf(p1) : (short)0;
            ap[2] = g0 ? (short)f2bf(p2) : (short)0;
            ap[3] = g0 ? (short)f2bf(p3) : (short)0;
            ap[4] = g0 ? (short)f2bf(p4) : (short)0;
            ap[5] = g0 ? (short)f2bf(p5) : (short)0;
            ap[6] = g0 ? (short)0x3F80 : (short)0;   // bf16(1.0) -> b1 rides k==6
            ap[7] = 0;
            apeQ[q] = ap;
        }

        // ---- layer 1 ----
        float g1[2][4][4];
#pragma unroll
        for (int q = 0; q < 2; ++q)
#pragma unroll
            for (int m = 0; m < 4; ++m) {
                f32x4 c = __builtin_amdgcn_mfma_f32_16x16x32_bf16(w1f[m * 64], apeQ[q], zero, 0, 0, 0);
#pragma unroll
                for (int r = 0; r < 4; ++r) g1[q][m][r] = gelu_tanh(c[r]);
            }

        // ---- B2 frags: pack-then-permute ----
        bf16x8 B2[2][2];
#pragma unroll
        for (int q = 0; q < 2; ++q)
#pragma unroll
            for (int kt = 0; kt < 2; ++kt) {
                int pk0[2], pk1[2];
#pragma unroll
                for (int rp = 0; rp < 2; ++rp) {
                    pk0[rp] = cvt_pk_bf16(g1[q][2 * kt + 0][2 * rp], g1[q][2 * kt + 0][2 * rp + 1]);
                    pk1[rp] = cvt_pk_bf16(g1[q][2 * kt + 1][2 * rp], g1[q][2 * kt + 1][2 * rp + 1]);
                }
                i32x4 w;
#pragma unroll
                for (int h = 0; h < 2; ++h) {
                    int ah = h ? addrH1 : addrH0;
#pragma unroll
                    for (int rp = 0; rp < 2; ++rp) {
                        int vA = bperm(ah, pk0[rp]);
                        int vB = bperm(ah, pk1[rp]);
                        w[h * 2 + rp] = selHi ? vB : vA;
                    }
                }
                B2[q][kt] = __builtin_bit_cast(bf16x8, w);
            }

        // ---- layer 2 ----
        float g2[2][4][4];
#pragma unroll
        for (int q = 0; q < 2; ++q)
#pragma unroll
            for (int m = 0; m < 4; ++m) {
                f32x4 c = __builtin_amdgcn_mfma_f32_16x16x32_bf16(whf[(2 * m + 0) * 64], B2[q][0], zero, 0, 0, 0);
                c = __builtin_amdgcn_mfma_f32_16x16x32_bf16(whf[(2 * m + 1) * 64], B2[q][1], c, 0, 0, 0);
                float4 b4 = *reinterpret_cast<const float4*>(&bhs[m * 16 + grp * 4]);
                float bb[4] = {b4.x, b4.y, b4.z, b4.w};
#pragma unroll
                for (int r = 0; r < 4; ++r) g2[q][m][r] = gelu_tanh(c[r] + bb[r]);
            }

        // ---- B3 frags ----
        bf16x8 B3[2][2];
#pragma unroll
        for (int q = 0; q < 2; ++q)
#pragma unroll
            for (int kt = 0; kt < 2; ++kt) {
                int pk0[2], pk1[2];
#pragma unroll
                for (int rp = 0; rp < 2; ++rp) {
                    pk0[rp] = cvt_pk_bf16(g2[q][2 * kt + 0][2 * rp], g2[q][2 * kt + 0][2 * rp + 1]);
                    pk1[rp] = cvt_pk_bf16(g2[q][2 * kt + 1][2 * rp], g2[q][2 * kt + 1][2 * rp + 1]);
                }
                i32x4 w;
#pragma unroll
                for (int h = 0; h < 2; ++h) {
                    int ah = h ? addrH1 : addrH0;
#pragma unroll
                    for (int rp = 0; rp < 2; ++rp) {
                        int vA = bperm(ah, pk0[rp]);
                        int vB = bperm(ah, pk1[rp]);
                        w[h * 2 + rp] = selHi ? vB : vA;
                    }
                }
                B3[q][kt] = __builtin_bit_cast(bf16x8, w);
            }

        // ---- bo contribution: msg = BOF @ X^T (x already bf16) ----
        f32x4 msg[2];
#pragma unroll
        for (int q = 0; q < 2; ++q) {
            bf16x8 xb;
#pragma unroll
            for (int j = 0; j < 8; ++j) {
                short v = (grp == 0) ? (short)xA[q][j] : ((grp == 1) ? (short)xB[q][j] : (short)0);
                xb[j] = v;
            }
            msg[q] = __builtin_amdgcn_mfma_f32_16x16x32_bf16(bofr, xb, zero, 0, 0, 0);
        }

        // ---- layer 3 + einsum ----
#pragma unroll
        for (int i = 0; i < 16; ++i)
#pragma unroll
            for (int q = 0; q < 2; ++q) {
                f32x4 c = __builtin_amdgcn_mfma_f32_16x16x32_bf16(wof[(2 * i + 0) * 64], B3[q][0], zero, 0, 0, 0);
                c = __builtin_amdgcn_mfma_f32_16x16x32_bf16(wof[(2 * i + 1) * 64], B3[q][1], c, 0, 0, 0);
                float xf = bf2f(i < 8 ? xA[q][i] : xB[q][i - 8]);
#pragma unroll
                for (int r = 0; r < 4; ++r)
                    msg[q][r] = fmaf(xf, c[r], msg[q][r]);
            }

        // ---- transpose msg across lanes -> line-packed atomics (64B/edge) ----
#pragma unroll
        for (int q = 0; q < 2; ++q) {
#pragma unroll
            for (int rd = 0; rd < 4; ++rd) {
                int u0 = bperm(addrT[rd], fbits(msg[q][0]));
                int u1 = bperm(addrT[rd], fbits(msg[q][1]));
                int u2 = bperm(addrT[rd], fbits(msg[q][2]));
                int u3 = bperm(addrT[rd], fbits(msg[q][3]));
                int v  = (selT == 0) ? u0 : (selT == 1) ? u1 : (selT == 2) ? u2 : u3;
                int dv = bperm(addrD[rd], dQ[q]);
                atomicAdd(out + (size_t)dv * 16 + er, ibits(v));
            }
        }
    }
}

extern "C" void kernel_launch(void* const* d_in, const int* in_sizes, int n_in,
                              void* d_out, int out_size, void* d_ws, size_t ws_size,
                              hipStream_t stream) {
    const float* x   = (const float*)d_in[0];
    const float* pos = (const float*)d_in[1];
    const int*   ei  = (const int*)d_in[2];
    const float* W1  = (const float*)d_in[3];
    const float* b1  = (const float*)d_in[4];
    const float* Wh  = (const float*)d_in[5];
    const float* bh  = (const float*)d_in[6];
    const float* Wo  = (const float*)d_in[7];
    const float* bo  = (const float*)d_in[8];
    float* out = (float*)d_out;
    unsigned short* xbf = (unsigned short*)d_ws;   // 1.6 MB bf16 x-table

    prep_kernel<<<(NPTS * 16 + 255) / 256, 256, 0, stream>>>(x, out, xbf);
    edge_mfma_kernel<<<NBLK, 512, 0, stream>>>(
        xbf, pos, ei, W1, b1, Wh, bh, Wo, bo, out);
}